// Round 1
// baseline (144.424 us; speedup 1.0000x reference)
//
#include <hip/hip_runtime.h>

#define NTHREADS 256
#define NBLOCKS 1792   // 7 blocks/CU on 256 CUs; 1,376,256 groups / 458,752 threads = exactly 3 each

__device__ __forceinline__ float wave_reduce(float v) {
    #pragma unroll
    for (int off = 32; off > 0; off >>= 1) v += __shfl_down(v, off, 64);
    return v;
}

__device__ __forceinline__ float block_reduce(float v) {
    v = wave_reduce(v);
    __shared__ float smem[NTHREADS / 64];
    const int lane = threadIdx.x & 63;
    const int wave = threadIdx.x >> 6;
    if (lane == 0) smem[wave] = v;
    __syncthreads();
    float s = 0.f;
    if (threadIdx.x == 0) {
        #pragma unroll
        for (int w = 0; w < NTHREADS / 64; ++w) s += smem[w];
    }
    return s;
}

// Each "group" = 4 consecutive triples = 12 consecutive floats = 3 float4.
// A thread loads 3 float4 from pred + 3 from target (6 independent 16B loads,
// no LDS, no barriers) and regroups into triples in registers.
__global__ __launch_bounds__(NTHREADS) void dis_partial_kernel(
    const float4* __restrict__ p4, const float4* __restrict__ t4,
    const float* __restrict__ pred, const float* __restrict__ targ,
    float* __restrict__ partials, int ngroup, int ntrip) {
    const int nth = gridDim.x * NTHREADS;
    float acc = 0.f;

    for (int g = blockIdx.x * NTHREADS + threadIdx.x; g < ngroup; g += nth) {
        const int b = 3 * g;
        const float4 pa = p4[b + 0];
        const float4 pb = p4[b + 1];
        const float4 pc = p4[b + 2];
        const float4 qa = t4[b + 0];
        const float4 qb = t4[b + 1];
        const float4 qc = t4[b + 2];

        const float d0  = pa.x - qa.x;
        const float d1  = pa.y - qa.y;
        const float d2  = pa.z - qa.z;
        const float d3  = pa.w - qa.w;
        const float d4  = pb.x - qb.x;
        const float d5  = pb.y - qb.y;
        const float d6  = pb.z - qb.z;
        const float d7  = pb.w - qb.w;
        const float d8  = pc.x - qc.x;
        const float d9  = pc.y - qc.y;
        const float d10 = pc.z - qc.z;
        const float d11 = pc.w - qc.w;

        acc += sqrtf(d0 * d0 + d1 * d1 + d2 * d2);
        acc += sqrtf(d3 * d3 + d4 * d4 + d5 * d5);
        acc += sqrtf(d6 * d6 + d7 * d7 + d8 * d8);
        acc += sqrtf(d9 * d9 + d10 * d10 + d11 * d11);
    }

    // Generic scalar tail (empty here: ntrip = 5,505,024 = 4 * 1,376,256).
    for (int j = ngroup * 4 + blockIdx.x * NTHREADS + threadIdx.x; j < ntrip;
         j += nth) {
        const float dx = pred[3 * j + 0] - targ[3 * j + 0];
        const float dy = pred[3 * j + 1] - targ[3 * j + 1];
        const float dz = pred[3 * j + 2] - targ[3 * j + 2];
        acc += sqrtf(dx * dx + dy * dy + dz * dz);
    }

    const float s = block_reduce(acc);
    if (threadIdx.x == 0) partials[blockIdx.x] = s;
}

__global__ __launch_bounds__(NTHREADS) void dis_finalize_kernel(
    const float* __restrict__ partials, float* __restrict__ out,
    int nblocks, float scale) {
    float acc = 0.f;
    for (int i = threadIdx.x; i < nblocks; i += NTHREADS) acc += partials[i];
    const float s = block_reduce(acc);
    if (threadIdx.x == 0) out[0] = s * scale;  // full overwrite of poisoned d_out
}

extern "C" void kernel_launch(void* const* d_in, const int* in_sizes, int n_in,
                              void* d_out, int out_size, void* d_ws, size_t ws_size,
                              hipStream_t stream) {
    const float* pred = (const float*)d_in[0];
    const float* targ = (const float*)d_in[1];
    float* out = (float*)d_out;
    float* partials = (float*)d_ws;  // NBLOCKS floats, each block owns its slot

    const int n = in_sizes[0];          // B * 63 = 16,515,072 floats
    const int ntrip = n / 3;            // 5,505,024 joint distances
    const int ngroup = ntrip / 4;       // 1,376,256 groups of 4 triples (exact)
    const float scale = 1.0f / (float)ntrip;

    dis_partial_kernel<<<NBLOCKS, NTHREADS, 0, stream>>>(
        (const float4*)pred, (const float4*)targ, pred, targ, partials, ngroup, ntrip);
    dis_finalize_kernel<<<1, NTHREADS, 0, stream>>>(partials, out, NBLOCKS, scale);
}